// Round 4
// baseline (423.768 us; speedup 1.0000x reference)
//
#include <hip/hip_runtime.h>

typedef _Float16 f16;
typedef f16 f16x8 __attribute__((ext_vector_type(8)));
typedef float f32x4 __attribute__((ext_vector_type(4)));

// workspace layout (bytes); proven ws_size >= 193,019,904 (round-2 path ran)
#define OFF_SMOD  0u            // [8][512] float
#define OFF_SSQ   16384u        // [8][512] float
#define OFF_DEMOD 32768u        // [8][512] float
#define OFF_WSQ   49152u        // [512][512] float
#define OFF_WPAR  1097728u      // [9][16][512][32] f16 (slot, fi-chunk, fo, ch)
#define OFF_XP    5816320u      // [8*4356 + 1][512] f16 (flat padded planes + zero guard row)
#define XP_BYTES  35685376u     // (8*4356+1)*512*2
#define OFF_YP    41501696u     // [4][8][512][PLANE] f16 parity planes
#define PLANE     4560          // 67*68 = 4556, padded to 16B multiple
// end = 41501696 + 16384*4560*2 = 190,923,776 <= 193,019,904  OK

// ---------------- style modulation: s, s^2 ----------------
__global__ void style_kernel(const float* __restrict__ style, const float* __restrict__ mod_w,
                             const float* __restrict__ mod_b, float* __restrict__ smod,
                             float* __restrict__ ssq) {
    int b = blockIdx.x;
    int fi = threadIdx.x;  // 512 threads
    __shared__ float st[512];
    st[fi] = style[b * 512 + fi];
    __syncthreads();
    float sum = 0.f;
    const float* mw = mod_w + (size_t)fi * 512;
    for (int d = 0; d < 512; ++d) sum += st[d] * mw[d];
    float s = sum * 0.04419417382415922f /* 512^-0.5 */ + mod_b[fi];
    smod[b * 512 + fi] = s * 0.014731391274719741f /* 4608^-0.5 */;
    ssq[b * 512 + fi] = s * s;
}

// ---------------- wsq[fo][fi] = sum_k w^2 ----------------
__global__ void wsq_kernel(const float* __restrict__ w, float* __restrict__ wsq) {
    int fo = blockIdx.x;
    int fi = threadIdx.x;  // 512
    const float* p = w + ((size_t)fo * 512 + fi) * 9;
    float s = 0.f;
#pragma unroll
    for (int k = 0; k < 9; ++k) { float v = p[k]; s += v * v; }
    wsq[fo * 512 + fi] = s;
}

// ---------------- demod[b][fo] ----------------
__global__ void demod_kernel(const float* __restrict__ ssq, const float* __restrict__ wsq,
                             float* __restrict__ demod) {
    int b = blockIdx.x >> 1;
    int fo = (blockIdx.x & 1) * 256 + threadIdx.x;
    __shared__ float sq[512];
    for (int i = threadIdx.x; i < 512; i += 256) sq[i] = ssq[b * 512 + i];
    __syncthreads();
    float sum = 0.f;
    const float* wr = wsq + (size_t)fo * 512;
    for (int fi = 0; fi < 512; ++fi) sum += sq[fi] * wr[fi];
    demod[b * 512 + fo] = rsqrtf(sum * (1.0f / 4608.0f) + 1e-8f);
}

// ---------------- x' = x * (w_scale*s), NCHW fp32 -> padded NHWC f16 ----------------
__global__ void xp_kernel(const float* __restrict__ x, const float* __restrict__ smod,
                          f16* __restrict__ xp) {
    int id = blockIdx.x;  // 8b * 64h * 8fc = 4096
    int fc = id & 7;
    int h = (id >> 3) & 63;
    int b = id >> 9;
    int fi0 = fc * 64;
    __shared__ f16 tile[64 * 65];
    int tid = threadIdx.x;
#pragma unroll
    for (int it = 0; it < 16; ++it) {
        int e = it * 256 + tid;
        int i = e >> 6, wc = e & 63;
        float v = x[(((size_t)(b * 512 + fi0 + i)) * 64 + h) * 64 + wc];
        tile[i * 65 + wc] = (f16)(v * smod[b * 512 + fi0 + i]);
    }
    __syncthreads();
#pragma unroll
    for (int it = 0; it < 16; ++it) {
        int e = it * 256 + tid;
        int wc = e >> 6, i = e & 63;
        xp[((size_t)(b * 4356 + (h + 1) * 66 + (wc + 1))) * 512 + fi0 + i] = tile[i * 65 + wc];
    }
}

// ---------------- wpar2[slot][fi-chunk][fo][32ch] ----------------
__global__ void wpar2_kernel(const float* __restrict__ w, f16* __restrict__ wpar2) {
    // slot -> w flat index (ky*3+kx):
    // c0(ee): (2,2),(2,0),(0,2),(0,0); c1(eo): (2,1),(0,1); c2(oe): (1,2),(1,0); c3(oo): (1,1)
    const int wi_[9] = {8, 6, 2, 0, 7, 1, 5, 3, 4};
    int fo = blockIdx.x;
#pragma unroll
    for (int half = 0; half < 2; ++half) {
        int fi = half * 256 + threadIdx.x;
        const float* p = w + ((size_t)fo * 512 + fi) * 9;
        int fc = fi >> 5, ch = fi & 31;
#pragma unroll
        for (int s = 0; s < 9; ++s)
            wpar2[(((size_t)s * 16 + fc) * 512 + fo) * 32 + ch] = (f16)p[wi_[s]];
    }
}

// ---------------- zero row 0 and col 0 of each parity plane ----------------
__global__ void ring2_kernel(f16* __restrict__ P) {
    int idx = blockIdx.x * 256 + threadIdx.x;
    if (idx >= 16384 * 133) return;
    int slab = idx / 133, r = idx - slab * 133;
    f16* base = P + (size_t)slab * PLANE;
    if (r < 68) base[r] = (f16)0.f;          // row 0
    else base[(r - 67) * 68] = (f16)0.f;     // col 0, rows 1..65
}

// ---------------- pass 1: pipelined flattened-N shifted implicit GEMM ----------------
template <int C>
__device__ __forceinline__ void tconv_body(const f16* __restrict__ wpar2, const f16* __restrict__ xp,
                                           f16* __restrict__ P, f16* Xs, int b, int fg, int n0t) {
    constexpr int NT   = (C == 0) ? 4 : (C == 3) ? 1 : 2;
    constexpr int SB   = (C == 0) ? 0 : (C == 1) ? 4 : (C == 2) ? 6 : 8;
    constexpr int LB   = (C <= 1) ? 67 : (C == 2) ? 1 : 0;    // local-row base
    constexpr int WOFF = (C <= 1) ? 0 : (C == 2) ? 66 : 67;   // window start rel n0
    constexpr int WLEN = (C <= 1) ? 195 : (C == 2) ? 129 : 128;
    constexpr int CH4  = WLEN * 4;            // 16B units per buffer (logical)
    constexpr int CH4P = (CH4 + 7) & ~7;      // padded: swizzle can reach unit|7
    constexpr int Q    = 16 * NT;
    constexpr int offs[4] = {(C == 0) ? -67 : (C == 1) ? -66 : (C == 2) ? -1 : 0,
                             (C == 0) ? -66 : 0, -1, 0};

    int tid = threadIdx.x, lane = tid & 63, wave = tid >> 6;
    int wm = wave >> 1, wn = wave & 1, kb = lane >> 4, lr = lane & 15;
    int n0 = n0t << 7, fo0 = fg << 7;
    int WB = b * 4356 + n0 + WOFF;
    int bmax = b * 4356 + 4356;   // zero guard row

    f32x4 acc[4][4];
#pragma unroll
    for (int m = 0; m < 4; ++m)
#pragma unroll
        for (int n = 0; n < 4; ++n) acc[m][n] = (f32x4){0.f, 0.f, 0.f, 0.f};

    int4 xr2[2][4];
    f16x8 afr[3][4], bfr[2][4];

    const f16* abase = wpar2 + ((size_t)(fo0 + wm * 64 + lr)) * 32 + (size_t)kb * 8;
    auto loadA = [&](int q, f16x8* dst) {
        int fc = q / NT, tap = q - fc * NT;
        const f16* p = abase + (size_t)((SB + tap) * 16 + fc) * (512 * 32);
#pragma unroll
        for (int m = 0; m < 4; ++m) dst[m] = *(const f16x8*)(p + m * 16 * 32);
    };
    auto loadX = [&](int k, int4* xr) {
        int fi0 = k * 32;
#pragma unroll
        for (int it = 0; it < 4; ++it) {
            int idx = it * 256 + tid;
            int4 v = {0, 0, 0, 0};
            if (idx < CH4) {
                int r = idx >> 2, part = idx & 3;
                int pr = WB + r;
                if (pr <= bmax) v = *(const int4*)(xp + ((size_t)pr * 512 + fi0 + part * 8));
            }
            xr[it] = v;
        }
    };
    auto writeX = [&](int buf, const int4* xr) {
#pragma unroll
        for (int it = 0; it < 4; ++it) {
            int idx = it * 256 + tid;
            if (idx < CH4) {
                int r = idx >> 2, part = idx & 3;
                *(int4*)((char*)Xs + buf * (CH4P * 16) + (((r * 4 + part) ^ (r & 7)) << 4)) = xr[it];
            }
        }
    };
    auto readBF = [&](int buf, int tap, f16x8* dst) {
#pragma unroll
        for (int n = 0; n < 4; ++n) {
            int r = wn * 64 + n * 16 + lr + offs[tap] + LB;
            dst[n] = *(const f16x8*)((const char*)Xs + buf * (CH4P * 16) + (((r * 4 + kb) ^ (r & 7)) << 4));
        }
    };

    // prologue
    loadX(0, xr2[0]);
    loadA(0, afr[0]);
    loadA(1, afr[1 % 3]);
    writeX(0, xr2[0]);
    __syncthreads();
    loadX(1, xr2[1]);
    readBF(0, 0, bfr[0]);

#pragma unroll
    for (int k = 0; k < 16; ++k) {
        const int cur = k & 1;
        if (k < 14) loadX(k + 2, xr2[k & 1]);          // T14: issue a full k-step early
        if (k < 15) writeX(1 - cur, xr2[(k + 1) & 1]); // stage X(k+1) into other buffer
#pragma unroll
        for (int tap = 0; tap < NT - 1; ++tap) {
            const int q = k * NT + tap;
            if (q + 2 < Q) loadA(q + 2, afr[(q + 2) % 3]);
            readBF(cur, tap + 1, bfr[(q + 1) & 1]);
            __builtin_amdgcn_s_setprio(1);
#pragma unroll
            for (int m = 0; m < 4; ++m)
#pragma unroll
                for (int n = 0; n < 4; ++n)
                    acc[m][n] = __builtin_amdgcn_mfma_f32_16x16x32_f16(afr[q % 3][m], bfr[q & 1][n], acc[m][n], 0, 0, 0);
            __builtin_amdgcn_s_setprio(0);
        }
        {   // last tap: barrier first, then its MFMA covers the next-buffer read latency
            const int q = k * NT + NT - 1;
            if (k < 15) __syncthreads();
            if (q + 2 < Q) loadA(q + 2, afr[(q + 2) % 3]);
            if (k < 15) readBF(1 - cur, 0, bfr[(q + 1) & 1]);
            __builtin_amdgcn_s_setprio(1);
#pragma unroll
            for (int m = 0; m < 4; ++m)
#pragma unroll
                for (int n = 0; n < 4; ++n)
                    acc[m][n] = __builtin_amdgcn_mfma_f32_16x16x32_f16(afr[q % 3][m], bfr[q & 1][n], acc[m][n], 0, 0, 0);
            __builtin_amdgcn_s_setprio(0);
        }
    }

    // epilogue: invalid positions compute to natural zeros -> store unconditionally
    size_t slab = (size_t)(C * 8 + b) * 512;
#pragma unroll
    for (int m = 0; m < 4; ++m) {
#pragma unroll
        for (int j = 0; j < 4; ++j) {
            int fo = fo0 + wm * 64 + m * 16 + kb * 4 + j;   // C row = (lane>>4)*4 + j
            f16* pb = P + (slab + fo) * PLANE;
#pragma unroll
            for (int n = 0; n < 4; ++n) {
                int nn = n0 + wn * 64 + n * 16 + lr;        // C col = lane & 15
                int t = (nn * 993) >> 16;                   // n / 66
                int s = nn - t * 66;
                pb[(t + 1) * 68 + (s + 1)] = (f16)acc[m][n][j];
            }
        }
    }
}

__global__ __launch_bounds__(256, 2) void tconv2_kernel(const f16* __restrict__ wpar2,
                                                        const f16* __restrict__ xp,
                                                        f16* __restrict__ P) {
    __shared__ __align__(16) f16 Xs[2 * 784 * 8];   // 2 buffers * 784 units * 16B = 25088 B
    int id = blockIdx.x;                            // 4352 = 8b * 4c * 4fg * 34 n-tiles
    int b = id & 7;                                 // XCD swizzle: b <-> XCD
    int r = id >> 3;                                // 0..543
    int c = r / 136;
    int r2 = r - c * 136;
    int fg = r2 / 34;
    int n0t = r2 - fg * 34;
    switch (c) {
        case 0: tconv_body<0>(wpar2, xp, P, Xs, b, fg, n0t); break;
        case 1: tconv_body<1>(wpar2, xp, P, Xs, b, fg, n0t); break;
        case 2: tconv_body<2>(wpar2, xp, P, Xs, b, fg, n0t); break;
        default: tconv_body<3>(wpar2, xp, P, Xs, b, fg, n0t); break;
    }
}

// ---------------- pass 2: separable FIR [.25 .75 .75 .25]^2 + demod, one block per (b,fo) ----------------
__global__ __launch_bounds__(256, 4) void fir3_kernel(const f16* __restrict__ P,
                                                      const float* __restrict__ demod,
                                                      float* __restrict__ out) {
    int bid = blockIdx.x;          // 4096: b = bid&7 (matches tconv's XCD placement), fo = bid>>3
    int b = bid & 7, fo = bid >> 3;
    __shared__ __align__(16) f16 yr[4][4488];   // 4 parity planes, rows 0..65 x 68 cols
    const size_t pstep = (size_t)8 * 512 * PLANE;
    int tid = threadIdx.x;
    const f16* src0 = P + ((size_t)(b * 512 + fo)) * PLANE;
#pragma unroll
    for (int c = 0; c < 4; ++c) {
        const int4* src = (const int4*)(src0 + c * pstep);
        int4* dst = (int4*)(&yr[c][0]);
#pragma unroll
        for (int it = 0; it < 3; ++it) {
            int idx = it * 256 + tid;
            if (idx < 561) dst[idx] = src[idx];
        }
    }
    __syncthreads();
    float dm = demod[b * 512 + fo];
    int OX = tid & 127, rg = tid >> 7;
    int OYb = rg * 64;
    int e = OX & 1;
    // per-tap (parity-plane, col) constant offsets into flat yr
    int c0o = (1 - e) * 4488 + (((OX - 1) >> 1) + 1);
    int c1o = e * 4488 + ((OX >> 1) + 1);
    int c2o = (1 - e) * 4488 + (((OX + 1) >> 1) + 1);
    int c3o = e * 4488 + (((OX + 2) >> 1) + 1);
    const f16* yf = &yr[0][0];
    size_t obase = ((size_t)(b * 512 + fo)) * 16384 + OX;
    float h0 = 0.f, h1 = 0.f, h2 = 0.f, h3 = 0.f;
#pragma unroll 4
    for (int i = 0; i < 67; ++i) {
        int oy = OYb - 1 + i;
        int base = (oy & 1) * (2 * 4488) + ((oy >> 1) + 1) * 68;
        float h = 0.25f * ((float)yf[base + c0o] + (float)yf[base + c3o])
                + 0.75f * ((float)yf[base + c1o] + (float)yf[base + c2o]);
        h0 = h1; h1 = h2; h2 = h3; h3 = h;
        if (i >= 3) {
            float a = 0.25f * (h0 + h3) + 0.75f * (h1 + h2);
            out[obase + (size_t)(OYb + i - 3) * 128] = a * dm;
        }
    }
}

extern "C" void kernel_launch(void* const* d_in, const int* in_sizes, int n_in,
                              void* d_out, int out_size, void* d_ws, size_t ws_size,
                              hipStream_t stream) {
    const float* x = (const float*)d_in[0];
    const float* style = (const float*)d_in[1];
    const float* w = (const float*)d_in[2];
    const float* mod_w = (const float*)d_in[3];
    const float* mod_b = (const float*)d_in[4];
    float* out = (float*)d_out;

    char* ws = (char*)d_ws;
    float* smod = (float*)(ws + OFF_SMOD);
    float* ssq = (float*)(ws + OFF_SSQ);
    float* demod = (float*)(ws + OFF_DEMOD);
    float* wsq = (float*)(ws + OFF_WSQ);
    f16* wpar2 = (f16*)(ws + OFF_WPAR);
    f16* xp = (f16*)(ws + OFF_XP);
    f16* P = (f16*)(ws + OFF_YP);

    style_kernel<<<8, 512, 0, stream>>>(style, mod_w, mod_b, smod, ssq);
    wsq_kernel<<<512, 512, 0, stream>>>(w, wsq);
    demod_kernel<<<16, 256, 0, stream>>>(ssq, wsq, demod);
    wpar2_kernel<<<512, 256, 0, stream>>>(w, wpar2);
    hipMemsetAsync(xp, 0, XP_BYTES, stream);
    xp_kernel<<<4096, 256, 0, stream>>>(x, smod, xp);
    ring2_kernel<<<8512, 256, 0, stream>>>(P);
    tconv2_kernel<<<4352, 256, 0, stream>>>(wpar2, xp, P);
    fir3_kernel<<<4096, 256, 0, stream>>>(P, demod, out);
}